// Round 9
// baseline (235.295 us; speedup 1.0000x reference)
//
#include <hip/hip_runtime.h>
#include <hip/hip_bf16.h>
#include <cmath>

// I/O: all inputs float32 (per reference setup_inputs), output float32.
// Internal compute: bf16 MFMA with fp32 accumulation.
//
// Workspace layout (64 MB total):
//  [0,16M)   WqkvT  [4096][2048] bf16   (rows: 0-2047 WqT, 2048-3071 WkT, 3072-4095 WvT)
//  [16,24M)  WoT    [2048][2048] bf16
//  [24,40M)  QKVraw [2048][4096] bf16
//  [40,48M)  Qn     [2048][2048] bf16   (post rms+rope, pre-scaled by QK_SCALE*log2e)
//  [48,52M)  Kn     [2048][1024] bf16
//  [52,56M)  Vt     [1024][2048] bf16   ([hkv*128 d][s])
//  [56,64M)  hsb    [2048][2048] bf16   (live: kernels 1-2)   }  overlaid,
//  [56,64M)  AT     [2048][2048] bf16   (live: kernels 4-5)   }  disjoint liveness

typedef __bf16 bf16x8 __attribute__((ext_vector_type(8)));
typedef float  f32x4  __attribute__((ext_vector_type(4)));

#define S_LEN    2048
#define NH       16
#define NKV      8
#define HDIM     128
#define WIN      1024
// QK_SCALE * log2(e): scores computed directly in log2 domain -> exp2
#define QK_SCALE_L2E 0.12751744595f
#define RMS_EPS  1e-6f

__device__ __forceinline__ void gld16(void* lds, const void* g) {
    __builtin_amdgcn_global_load_lds(
        (const __attribute__((address_space(1))) unsigned int*)g,
        (__attribute__((address_space(3))) unsigned int*)lds, 16, 0, 0);
}

__device__ __forceinline__ unsigned short f2bu(float x) {
    __hip_bfloat16 h = __float2bfloat16(x);
    return *(unsigned short*)&h;
}

// ---------------------------------------------------------------------------
// Fused: weight transpose + f32->bf16 (blocks 0..3071)  AND
//        hidden_states f32->bf16 convert (blocks 3072..5119).
// ---------------------------------------------------------------------------
__global__ __launch_bounds__(256) void trans_cvt_kernel(
    const float* __restrict__ Wq, const float* __restrict__ Wk,
    const float* __restrict__ Wv, const float* __restrict__ Wo,
    const float* __restrict__ hs,
    __hip_bfloat16* __restrict__ WqkvT, __hip_bfloat16* __restrict__ WoT,
    __hip_bfloat16* __restrict__ hsb)
{
    __shared__ __attribute__((aligned(16))) unsigned short tile[64][72]; // 144B rows
    int id = blockIdx.x;
    if (id >= 3072) {   // ---- hidden_states convert: 8 elems/thread ----
        size_t i = ((size_t)(id - 3072) * 256 + threadIdx.x) * 8;
        float4 a = *(const float4*)(hs + i);
        float4 b = *(const float4*)(hs + i + 4);
        unsigned short u[8] = { f2bu(a.x), f2bu(a.y), f2bu(a.z), f2bu(a.w),
                                f2bu(b.x), f2bu(b.y), f2bu(b.z), f2bu(b.w) };
        *(uint4*)(hsb + i) = *(uint4*)u;
        return;
    }
    const float* src; __hip_bfloat16* dst; int N, kt, nt;
    if (id < 1024)      { src = Wq; dst = WqkvT;                          N = 2048; kt = id >> 5;          nt = id & 31; }
    else if (id < 1536) { src = Wk; dst = WqkvT + (size_t)2048*2048;      N = 1024; kt = (id-1024) >> 4;   nt = (id-1024) & 15; }
    else if (id < 2048) { src = Wv; dst = WqkvT + (size_t)3072*2048;      N = 1024; kt = (id-1536) >> 4;   nt = (id-1536) & 15; }
    else                { src = Wo; dst = WoT;                            N = 2048; kt = (id-2048) >> 5;   nt = (id-2048) & 31; }
    int k0 = kt * 64, n0 = nt * 64;
    int tid = threadIdx.x;
#pragma unroll
    for (int p = 0; p < 2; ++p) {
        int c = p*256 + tid; int r = c >> 3, cc = (c & 7) * 8;
        const float* s = src + (size_t)(k0 + r)*N + n0 + cc;
        float4 a = *(const float4*)s;
        float4 b = *(const float4*)(s + 4);
        unsigned short u[8] = { f2bu(a.x), f2bu(a.y), f2bu(a.z), f2bu(a.w),
                                f2bu(b.x), f2bu(b.y), f2bu(b.z), f2bu(b.w) };
        *(uint4*)&tile[r][cc] = *(uint4*)u;
    }
    __syncthreads();
#pragma unroll
    for (int p = 0; p < 2; ++p) {
        int c = p*256 + tid; int r2 = c >> 3, c2 = (c & 7) * 8;
        uint4 o;
        o.x = tile[c2+0][r2] | ((unsigned)tile[c2+1][r2] << 16);
        o.y = tile[c2+2][r2] | ((unsigned)tile[c2+3][r2] << 16);
        o.z = tile[c2+4][r2] | ((unsigned)tile[c2+5][r2] << 16);
        o.w = tile[c2+6][r2] | ((unsigned)tile[c2+7][r2] << 16);
        *(uint4*)(dst + (size_t)(n0 + r2)*2048 + k0 + c2) = o;
    }
}

// ---------------------------------------------------------------------------
// GEMM (4-wave): C[M][N] = A[M][K] * BT[N][K]^T.  BM=128 BN=128 BK=64,
// double-buffered global_load_lds staging, wave-tile 64x64 (0.5 reads/MFMA).
// XOR swizzle: chunk c of row r at slot c^(r&7) -> conflict-free ds_read_b128.
// ---------------------------------------------------------------------------
template <typename OT>
__global__ __launch_bounds__(256, 2) void gemm_bt_kernel(
    const __hip_bfloat16* __restrict__ A, const __hip_bfloat16* __restrict__ BT,
    OT* __restrict__ C, int M, int N, int K)
{
    __shared__ __attribute__((aligned(16))) __hip_bfloat16 As[2][128*64];  // 2x16KB
    __shared__ __attribute__((aligned(16))) __hip_bfloat16 Bs[2][128*64];  // 2x16KB
    const int tid  = threadIdx.x;
    const int lane = tid & 63;
    const int wave = tid >> 6;
    const int quad = lane >> 4, l15 = lane & 15;
    const int m0 = blockIdx.y * 128, n0 = blockIdx.x * 128;
    const int wm = (wave >> 1) * 64, wn = (wave & 1) * 64;
    const int sw = l15 & 7;

    f32x4 acc[4][4] = {};

    auto stage = [&](int b, int k0) {
#pragma unroll
        for (int p = 0; p < 4; ++p) {           // A: 128 rows x 8 slots of 16B
            int L = p*256 + tid;
            int r = L >> 3, s = L & 7;
            int cs = s ^ (r & 7);
            gld16((char*)&As[b][0] + L*16, A + (size_t)(m0 + r)*K + k0 + cs*8);
        }
#pragma unroll
        for (int p = 0; p < 4; ++p) {           // B: 128 rows x 8 slots of 16B
            int L = p*256 + tid;
            int r = L >> 3, s = L & 7;
            int cs = s ^ (r & 7);
            gld16((char*)&Bs[b][0] + L*16, BT + (size_t)(n0 + r)*K + k0 + cs*8);
        }
    };

    const int NT = K >> 6;
    stage(0, 0);
    int cur = 0;
    for (int kt = 0; kt < NT; ++kt, cur ^= 1) {
        __syncthreads();
        if (kt + 1 < NT) stage(cur ^ 1, (kt + 1) << 6);
#pragma unroll
        for (int ks = 0; ks < 2; ++ks) {
            const int slot = ((ks*4 + quad) ^ sw) * 8;
            bf16x8 af[4], bfr[4];
#pragma unroll
            for (int t = 0; t < 4; ++t) {
                af[t]  = *(const bf16x8*)(&As[cur][0] + (wm + t*16 + l15)*64 + slot);
                bfr[t] = *(const bf16x8*)(&Bs[cur][0] + (wn + t*16 + l15)*64 + slot);
            }
#pragma unroll
            for (int mt = 0; mt < 4; ++mt)
#pragma unroll
                for (int nt = 0; nt < 4; ++nt)
                    acc[mt][nt] = __builtin_amdgcn_mfma_f32_16x16x32_bf16(af[mt], bfr[nt], acc[mt][nt], 0, 0, 0);
        }
    }
#pragma unroll
    for (int mt = 0; mt < 4; ++mt)
#pragma unroll
        for (int nt = 0; nt < 4; ++nt)
#pragma unroll
            for (int r = 0; r < 4; ++r) {
                int row = m0 + wm + mt*16 + quad*4 + r;
                int col = n0 + wn + nt*16 + l15;
                if constexpr (__is_same(OT, float))
                    C[(size_t)row*N + col] = acc[mt][nt][r];
                else
                    C[(size_t)row*N + col] = __float2bfloat16(acc[mt][nt][r]);
            }
}

// ---------------------------------------------------------------------------
// GEMM (2-wave, BN=64): BM=128 BN=64 BK=64, wave-tile 64x64 (wave 0: rows
// 0-63, wave 1: rows 64-127).  Same 0.5 reads/MFMA ratio as the 4-wave
// version but grid doubles -> 2 blocks/CU for N=2048 outputs (the round-8
// out-GEMM ran at 1 block/CU and cost as much as QKV with half the FLOPs).
// LDS 48KB double-buffered; 2 blocks = 96KB fits.
// ---------------------------------------------------------------------------
template <typename OT>
__global__ __launch_bounds__(128, 2) void gemm_bt64_kernel(
    const __hip_bfloat16* __restrict__ A, const __hip_bfloat16* __restrict__ BT,
    OT* __restrict__ C, int M, int N, int K)
{
    __shared__ __attribute__((aligned(16))) __hip_bfloat16 As[2][128*64];  // 2x16KB
    __shared__ __attribute__((aligned(16))) __hip_bfloat16 Bs[2][64*64];   // 2x8KB
    const int tid  = threadIdx.x;
    const int lane = tid & 63;
    const int wave = tid >> 6;                  // 0..1
    const int quad = lane >> 4, l15 = lane & 15;
    const int m0 = blockIdx.y * 128, n0 = blockIdx.x * 64;
    const int wm = wave * 64;
    const int sw = l15 & 7;

    f32x4 acc[4][4] = {};

    auto stage = [&](int b, int k0) {
#pragma unroll
        for (int p = 0; p < 8; ++p) {           // A: 128 rows x 8 slots
            int L = p*128 + tid;
            int r = L >> 3, s = L & 7;
            int cs = s ^ (r & 7);
            gld16((char*)&As[b][0] + L*16, A + (size_t)(m0 + r)*K + k0 + cs*8);
        }
#pragma unroll
        for (int p = 0; p < 4; ++p) {           // B: 64 rows x 8 slots
            int L = p*128 + tid;
            int r = L >> 3, s = L & 7;
            int cs = s ^ (r & 7);
            gld16((char*)&Bs[b][0] + L*16, BT + (size_t)(n0 + r)*K + k0 + cs*8);
        }
    };

    const int NT = K >> 6;
    stage(0, 0);
    int cur = 0;
    for (int kt = 0; kt < NT; ++kt, cur ^= 1) {
        __syncthreads();
        if (kt + 1 < NT) stage(cur ^ 1, (kt + 1) << 6);
#pragma unroll
        for (int ks = 0; ks < 2; ++ks) {
            const int slot = ((ks*4 + quad) ^ sw) * 8;
            bf16x8 af[4], bfr[4];
#pragma unroll
            for (int t = 0; t < 4; ++t) {
                af[t]  = *(const bf16x8*)(&As[cur][0] + (wm + t*16 + l15)*64 + slot);
                bfr[t] = *(const bf16x8*)(&Bs[cur][0] + (t*16 + l15)*64 + slot);
            }
#pragma unroll
            for (int mt = 0; mt < 4; ++mt)
#pragma unroll
                for (int nt = 0; nt < 4; ++nt)
                    acc[mt][nt] = __builtin_amdgcn_mfma_f32_16x16x32_bf16(af[mt], bfr[nt], acc[mt][nt], 0, 0, 0);
        }
    }
#pragma unroll
    for (int mt = 0; mt < 4; ++mt)
#pragma unroll
        for (int nt = 0; nt < 4; ++nt)
#pragma unroll
            for (int r = 0; r < 4; ++r) {
                int row = m0 + wm + mt*16 + quad*4 + r;
                int col = n0 + nt*16 + l15;
                if constexpr (__is_same(OT, float))
                    C[(size_t)row*N + col] = acc[mt][nt][r];
                else
                    C[(size_t)row*N + col] = __float2bfloat16(acc[mt][nt][r]);
            }
}

// ---------------------------------------------------------------------------
// Fused: RMSNorm+RoPE on Q,K rows of QKVraw (blocks 0..2047, one s each)
//        AND V transpose QKVraw -> Vt (blocks 2048..2559, 64x64 tiles).
// Q output pre-scaled by QK_SCALE*log2(e) (attention uses exp2 directly).
// ---------------------------------------------------------------------------
__global__ __launch_bounds__(256) void rms_vt_kernel(
    const __hip_bfloat16* __restrict__ qkv,
    const float* __restrict__ cosb, const float* __restrict__ sinb,
    const float* __restrict__ qsc,  const float* __restrict__ ksc,
    __hip_bfloat16* __restrict__ Qn, __hip_bfloat16* __restrict__ Kn,
    __hip_bfloat16* __restrict__ Vt)
{
    __shared__ __attribute__((aligned(16))) unsigned short tile[64][72];
    int id = blockIdx.x;
    if (id >= 2048) {   // ---- V transpose tile ----
        int t  = id - 2048;                 // 512 tiles: 32 (s) x 16 (v)
        int s0 = (t & 31) * 64;
        int v0 = (t >> 5) * 64;
        int tid = threadIdx.x;
#pragma unroll
        for (int p = 0; p < 2; ++p) {
            int c = p*256 + tid; int r = c >> 3, cc = (c & 7) * 8;
            uint4 v = *(const uint4*)(qkv + (size_t)(s0 + r)*4096 + 3072 + v0 + cc);
            *(uint4*)&tile[r][cc] = v;
        }
        __syncthreads();
#pragma unroll
        for (int p = 0; p < 2; ++p) {
            int c = p*256 + tid; int r2 = c >> 3, c2 = (c & 7) * 8;
            uint4 o;
            o.x = tile[c2+0][r2] | ((unsigned)tile[c2+1][r2] << 16);
            o.y = tile[c2+2][r2] | ((unsigned)tile[c2+3][r2] << 16);
            o.z = tile[c2+4][r2] | ((unsigned)tile[c2+5][r2] << 16);
            o.w = tile[c2+6][r2] | ((unsigned)tile[c2+7][r2] << 16);
            *(uint4*)(Vt + (size_t)(v0 + r2)*2048 + s0 + c2) = o;
        }
        return;
    }
    // ---- RMSNorm + RoPE ----
    int s = id;
    int wave = threadIdx.x >> 6, lane = threadIdx.x & 63;
    float c1 = cosb[s*128 + lane];
    float c2 = cosb[s*128 + 64 + lane];
    float s1 = sinb[s*128 + lane];
    float s2 = sinb[s*128 + 64 + lane];
    for (int u = wave; u < 24; u += 4) {
        bool isq = (u < 16);
        int h = isq ? u : u - 16;
        const __hip_bfloat16* x = qkv + (size_t)s*4096 + (isq ? h*128 : 2048 + h*128);
        float x1 = (float)x[lane], x2 = (float)x[lane + 64];
        float ss = x1*x1 + x2*x2;
#pragma unroll
        for (int off = 32; off; off >>= 1) ss += __shfl_xor(ss, off);
        float r = rsqrtf(ss * (1.0f/128.0f) + RMS_EPS);
        if (isq) r *= QK_SCALE_L2E;        // fold attn scale + log2e into Q
        const float* sc = isq ? qsc : ksc;
        float y1 = x1 * r * sc[lane];
        float y2 = x2 * r * sc[lane + 64];
        float o1 = y1*c1 - y2*s1;   // d < 64:  x*c - x[d+64]*s
        float o2 = y2*c2 + y1*s2;   // d >= 64: x*c + x[d-64]*s
        __hip_bfloat16* dst = isq ? (Qn + (size_t)s*2048 + h*128)
                                  : (Kn + (size_t)s*1024 + h*128);
        dst[lane]      = __float2bfloat16(o1);
        dst[lane + 64] = __float2bfloat16(o2);
    }
}

// ---------------------------------------------------------------------------
// Flash attention, sliding-window causal — round 9: GQA head-pair blocks.
//  * Block = (kv-head hk, 64 q-rows).  Waves 0,1 -> q-head 2hk; waves 2,3
//    -> q-head 2hk+1; each wave covers 32 q-rows (2 A-frags).  One K/V
//    staging now feeds 2x the MFMA (GQA reuse) and staged bytes halve.
//  * Grid 8 kv-heads x 32 q-tiles = 256 blocks (1/CU); double-buffered
//    global_load_lds staging hides HBM latency under ~2700 cyc compute.
//  * No online max (scores bounded by RMS-norm); p=exp2(s), per-lane row
//    sums, single cross-lane reduce in epilogue.
// ---------------------------------------------------------------------------
__global__ __launch_bounds__(256, 1) void attn_kernel(
    const __hip_bfloat16* __restrict__ Qn,  // [S][2048], pre-scaled (log2 domain)
    const __hip_bfloat16* __restrict__ Kn,  // [S][1024]
    const __hip_bfloat16* __restrict__ Vt,  // [1024][S]
    __hip_bfloat16* __restrict__ O)         // [S][2048]
{
    __shared__ __attribute__((aligned(16))) __hip_bfloat16 Ksm[2][64*128];  // 2x16KB
    __shared__ __attribute__((aligned(16))) __hip_bfloat16 Vsm[2][128*64];  // 2x16KB
    __shared__ __attribute__((aligned(16))) __hip_bfloat16 P[4][32][76];    // ~19KB

    const int bx   = blockIdx.x;
    const int hk   = bx & 7;                  // kv head
    const int qb   = bx >> 3;                 // 0..31
    const int i0   = qb * 64;
    const int tid  = threadIdx.x, wave = tid >> 6, lane = tid & 63;
    const int quad = lane >> 4, l15 = lane & 15;
    const int hw   = 2*hk + (wave >> 1);      // this wave's q-head
    const int ibw  = i0 + (wave & 1) * 32;    // wave's 32-row base

    const __hip_bfloat16* Kh = Kn + hk * HDIM;              // row stride 1024
    const __hip_bfloat16* Vh = Vt + (size_t)(hk * HDIM) * 2048;

    // Q fragments (A-operand), 2 m-frags x 4 k-frags, fixed for the wave
    bf16x8 qf[2][4];
#pragma unroll
    for (int m = 0; m < 2; ++m) {
        const __hip_bfloat16* qbase = Qn + (size_t)(ibw + m*16 + l15)*2048 + hw*HDIM + quad*8;
#pragma unroll
        for (int kk = 0; kk < 4; ++kk) qf[m][kk] = *(const bf16x8*)(qbase + kk*32);
    }

    f32x4 o[2][8] = {};
    float lrow[2][4] = {};

    int j_lo = i0 - WIN; if (j_lo < 0) j_lo = 0;
    const int jstart = j_lo & ~63;
    const int jend   = i0;                    // diagonal tile start (i0 64-aligned)

    // ---- cooperative staging of one (K,V) tile pair into buffer b ----
    auto stage = [&](int b, int j0) {
#pragma unroll
        for (int p = 0; p < 4; ++p) {         // K: 64 rows x 16 chunks of 16B
            int L = p*256 + tid;
            int r = L >> 4;
            int c = (L & 15) ^ (r & 15);      // XOR swizzle
            gld16((char*)&Ksm[b][0] + L*16, Kh + (size_t)(j0 + r)*1024 + c*8);
        }
#pragma unroll
        for (int p = 0; p < 4; ++p) {         // V: 128 d-rows x 8 chunks of 16B
            int L = p*256 + tid;
            int dv = L >> 3;
            int c = (L & 7) ^ (dv & 7);       // XOR swizzle
            gld16((char*)&Vsm[b][0] + L*16, Vh + (size_t)dv*2048 + j0 + c*8);
        }
    };

    stage(0, jstart);
    int cur = 0;
    for (int j0 = jstart; j0 <= jend; j0 += 64, cur ^= 1) {
        __syncthreads();                      // drains staging vmcnt + syncs buffers
        if (j0 + 64 <= jend) stage(cur ^ 1, j0 + 64);

        // ---- S = Q K^T (32 x 64 per wave): 16 K-frag reads, 32 MFMA ----
        f32x4 sacc[2][4] = {};
#pragma unroll
        for (int nt = 0; nt < 4; ++nt) {
            const int r = nt*16 + l15;
#pragma unroll
            for (int kk = 0; kk < 4; ++kk) {
                const int cc = (kk*4 + quad) ^ l15;   // swizzled chunk
                bf16x8 kfr = *(const bf16x8*)(&Ksm[cur][0] + r*128 + cc*8);
                sacc[0][nt] = __builtin_amdgcn_mfma_f32_16x16x32_bf16(qf[0][kk], kfr, sacc[0][nt], 0, 0, 0);
                sacc[1][nt] = __builtin_amdgcn_mfma_f32_16x16x32_bf16(qf[1][kk], kfr, sacc[1][nt], 0, 0, 0);
            }
        }

        // ---- p = exp2(s), P write, per-lane row-sum ----
        const bool need_mask = (j0 + 63 > ibw) || (j0 < ibw + 31 - WIN);
        if (need_mask) {
#pragma unroll
            for (int m = 0; m < 2; ++m)
#pragma unroll
                for (int nt = 0; nt < 4; ++nt) {
                    int j = j0 + nt*16 + l15;
#pragma unroll
                    for (int r = 0; r < 4; ++r) {
                        int i = ibw + m*16 + quad*4 + r;
                        bool valid = (j <= i) && (i - j <= WIN);
                        float p = valid ? __builtin_exp2f(sacc[m][nt][r]) : 0.f;
                        lrow[m][r] += p;
                        P[wave][m*16 + quad*4 + r][nt*16 + l15] = __float2bfloat16(p);
                    }
                }
        } else {
#pragma unroll
            for (int m = 0; m < 2; ++m)
#pragma unroll
                for (int nt = 0; nt < 4; ++nt)
#pragma unroll
                    for (int r = 0; r < 4; ++r) {
                        float p = __builtin_exp2f(sacc[m][nt][r]);
                        lrow[m][r] += p;
                        P[wave][m*16 + quad*4 + r][nt*16 + l15] = __float2bfloat16(p);
                    }
        }

        // ---- O += P V: 16 V-frag reads, 4 P reads, 32 MFMA ----
#pragma unroll
        for (int ks = 0; ks < 2; ++ks) {
            bf16x8 pf0 = *(const bf16x8*)&P[wave][l15     ][ks*32 + quad*8];
            bf16x8 pf1 = *(const bf16x8*)&P[wave][16 + l15][ks*32 + quad*8];
#pragma unroll
            for (int dt = 0; dt < 8; ++dt) {
                const int dv = dt*16 + l15;
                const int cc = (ks*4 + quad) ^ (l15 & 7);
                bf16x8 vfr = *(const bf16x8*)(&Vsm[cur][0] + dv*64 + cc*8);
                o[0][dt] = __builtin_amdgcn_mfma_f32_16x16x32_bf16(pf0, vfr, o[0][dt], 0, 0, 0);
                o[1][dt] = __builtin_amdgcn_mfma_f32_16x16x32_bf16(pf1, vfr, o[1][dt], 0, 0, 0);
            }
        }
    }

    // ---- epilogue: reduce lrow across the 16 col-lanes, normalize, store ----
#pragma unroll
    for (int m = 0; m < 2; ++m)
#pragma unroll
        for (int r = 0; r < 4; ++r) {
            float l = lrow[m][r];
            l += __shfl_xor(l, 1);
            l += __shfl_xor(l, 2);
            l += __shfl_xor(l, 4);
            l += __shfl_xor(l, 8);
            float inv = 1.0f / l;
            int row = ibw + m*16 + quad*4 + r;
#pragma unroll
            for (int dt = 0; dt < 8; ++dt)
                O[(size_t)row*2048 + hw*HDIM + dt*16 + l15] = __float2bfloat16(o[m][dt][r] * inv);
        }
}

// ---------------------------------------------------------------------------
extern "C" void kernel_launch(void* const* d_in, const int* in_sizes, int n_in,
                              void* d_out, int out_size, void* d_ws, size_t ws_size,
                              hipStream_t stream)
{
    (void)in_sizes; (void)n_in; (void)out_size; (void)ws_size;
    const float* hs   = (const float*)d_in[0];
    const float* cosb = (const float*)d_in[1];
    const float* sinb = (const float*)d_in[2];
    const float* Wq   = (const float*)d_in[3];
    const float* Wk   = (const float*)d_in[4];
    const float* Wv   = (const float*)d_in[5];
    const float* Wo   = (const float*)d_in[6];
    const float* qs   = (const float*)d_in[7];
    const float* ks   = (const float*)d_in[8];

    char* ws = (char*)d_ws;
    __hip_bfloat16* WqkvT = (__hip_bfloat16*)(ws);
    __hip_bfloat16* WoT   = (__hip_bfloat16*)(ws + (16u << 20));
    __hip_bfloat16* QKV   = (__hip_bfloat16*)(ws + (24u << 20));
    __hip_bfloat16* Qn    = (__hip_bfloat16*)(ws + (40u << 20));
    __hip_bfloat16* Kn    = (__hip_bfloat16*)(ws + (48u << 20));
    __hip_bfloat16* Vt    = (__hip_bfloat16*)(ws + (52u << 20));
    __hip_bfloat16* hsb   = (__hip_bfloat16*)(ws + (56u << 20)); // overlaid with AT
    __hip_bfloat16* AT    = (__hip_bfloat16*)(ws + (56u << 20)); // disjoint liveness

    trans_cvt_kernel<<<dim3(5120), dim3(256), 0, stream>>>(Wq, Wk, Wv, Wo, hs, WqkvT, WoT, hsb);
    gemm_bt_kernel<__hip_bfloat16><<<dim3(32, 16), dim3(256), 0, stream>>>(hsb, WqkvT, QKV, 2048, 4096, 2048);
    rms_vt_kernel<<<dim3(2560), dim3(256), 0, stream>>>(QKV, cosb, sinb, qs, ks, Qn, Kn, Vt);
    attn_kernel<<<dim3(256), dim3(256), 0, stream>>>(Qn, Kn, Vt, AT);
    gemm_bt64_kernel<float><<<dim3(32, 16), dim3(128), 0, stream>>>(AT, WoT, (float*)d_out, 2048, 2048, 2048);
}